// Round 2
// baseline (522.276 us; speedup 1.0000x reference)
//
#include <hip/hip_runtime.h>
#include <hip/hip_bf16.h>

#define N_NODES 32768
#define NK      1048576      // N*K edges

typedef __bf16 bf16x8 __attribute__((ext_vector_type(8)));
typedef float  f32x4  __attribute__((ext_vector_type(4)));

// LDS layout (bytes), 64 KB total:
//  phase F/LN : pair0 fp32 [64][132]      @ 0      .. 33792
//               featsA bf16 [64][64] swz  @ 33792  .. 41984
//               wft    bf16 [128][64] swz @ 41984  .. 58368
//               meta   int  [64]          @ 58368  .. 58624
//  GEMM phase : X bf16 [64][128] swz      @ 0      .. 16384
//               W bf16 [128][128] swz     @ 16384  .. 49152
//               H bf16 [64][128] swz      @ 49152  .. 65536
#define FEATS_OFF 33792
#define WFT_OFF   41984
#define META_OFF  58368
#define WB_OFF    16384
#define HB_OFF    49152

static __device__ __forceinline__ unsigned short f2bf(float f) {
    union { float f; unsigned int u; } v; v.f = f;
    unsigned int u = v.u;
    return (unsigned short)((u + 0x7fffu + ((u >> 16) & 1u)) >> 16);   // RNE
}

// R[a*3+b] = e_{b}[a]  (columns e1,e2,e3) — matches jnp.stack([e1,e2,e3],axis=-1)
static __device__ __forceinline__ void make_frame(const float* __restrict__ p, float* __restrict__ R) {
    float v1x = p[6]-p[3], v1y = p[7]-p[4], v1z = p[8]-p[5];
    float v2x = p[0]-p[3], v2y = p[1]-p[4], v2z = p[2]-p[5];
    float i1 = 1.f/(sqrtf(v1x*v1x+v1y*v1y+v1z*v1z)+1e-6f);
    float e1x=v1x*i1, e1y=v1y*i1, e1z=v1z*i1;
    float dt = v2x*e1x+v2y*e1y+v2z*e1z;
    float u2x=v2x-dt*e1x, u2y=v2y-dt*e1y, u2z=v2z-dt*e1z;
    float i2 = 1.f/(sqrtf(u2x*u2x+u2y*u2y+u2z*u2z)+1e-6f);
    float e2x=u2x*i2, e2y=u2y*i2, e2z=u2z*i2;
    float e3x = e1y*e2z - e1z*e2y;
    float e3y = e1z*e2x - e1x*e2z;
    float e3z = e1x*e2y - e1y*e2x;
    R[0]=e1x; R[1]=e2x; R[2]=e3x;
    R[3]=e1y; R[4]=e2y; R[5]=e3y;
    R[6]=e1z; R[7]=e2z; R[8]=e3z;
}

// ---- prep: bf16-convert + transpose + pre-swizzle weights into ws ----
// w1t: value W1[p][h] at byte  half*32768 + hl*256 + ((2p)^((hl&7)<<4)),  h=half*128+hl
// w2t: value W2[h][p] at byte  half*32768 + p*256  + ((2hl)^((p&7)<<4))
// wft: value Wf[f][p] at byte  p*128 + ((2f)^((p&7)<<4)),  f<40 real else 0
__global__ void sd_prep_weights(const float* __restrict__ W1, const float* __restrict__ W2,
                                const float* __restrict__ Wd, const float* __restrict__ Wdir,
                                const float* __restrict__ Wrot, const float* __restrict__ Wvec,
                                unsigned short* __restrict__ w1t, unsigned short* __restrict__ w2t,
                                unsigned short* __restrict__ wft) {
    int i = blockIdx.x*256 + threadIdx.x;
    if (i < 32768) {
        int h = i >> 7, p = i & 127;
        int half = h >> 7, hl = h & 127;
        int byteoff = half*32768 + hl*256 + ((2*p) ^ ((hl&7)<<4));
        w1t[byteoff>>1] = f2bf(W1[p*256 + h]);
    } else if (i < 65536) {
        int idx = i - 32768;
        int p = idx >> 8, h = idx & 255;
        int half = h >> 7, hl = h & 127;
        int byteoff = half*32768 + p*256 + ((2*hl) ^ ((p&7)<<4));
        w2t[byteoff>>1] = f2bf(W2[h*128 + p]);
    } else if (i < 73728) {
        int idx = i - 65536;
        int p = idx >> 6, f = idx & 63;
        float v = 0.f;
        if (f < 16)      v = Wd[f*128+p];
        else if (f < 19) v = Wdir[(f-16)*128+p];
        else if (f < 28) v = Wrot[(f-19)*128+p];
        else if (f < 40) v = Wvec[(f-28)*128+p];
        int byteoff = p*128 + ((2*f) ^ ((p&7)<<4));
        wft[byteoff>>1] = f2bf(v);
    }
}

__global__ void sd_mask_kernel(const int* __restrict__ nbr, const float* __restrict__ mask,
                               float* __restrict__ outm) {
    int g = blockIdx.x*256 + threadIdx.x;
    if (g >= NK) return;
    int j = nbr[g];
    int n = g >> 5;
    float pm = mask[n] * mask[j & (N_NODES-1)] * ((j != -1) ? 1.f : 0.f);
    outm[g] = pm;
}

#define MFMA16(a,b,c) __builtin_amdgcn_mfma_f32_16x16x32_bf16((a),(b),(c),0,0,0)

__global__ __launch_bounds__(256, 2) void sd_fused_kernel(
    const float* __restrict__ pos, const int* __restrict__ nbr,
    const int* __restrict__ resi, const int* __restrict__ chain,
    const int* __restrict__ batch,
    const float* __restrict__ W_rel, const float* __restrict__ ln_scale,
    const float* __restrict__ ln_bias, const float* __restrict__ b1,
    const float* __restrict__ b2,
    const unsigned short* __restrict__ w1t, const unsigned short* __restrict__ w2t,
    const unsigned short* __restrict__ wft,
    float* __restrict__ out)
{
    __shared__ __align__(16) char smem[65536];
    const int t = threadIdx.x;
    const int row0 = blockIdx.x * 64;

    // ---------------- Phase F: per-edge features (threads 0..63), wft copy (64..255)
    if (t < 64) {
        const int g = row0 + t;
        const int n = g >> 5;
        const int j = nbr[g] & (N_NODES - 1);
        float pn[12], pj[12];
        #pragma unroll
        for (int i = 0; i < 12; ++i) { pn[i] = pos[n*12+i]; pj[i] = pos[j*12+i]; }
        float Rn[9], Rj[9];
        make_frame(pn, Rn); make_frame(pj, Rj);
        float dx = pj[3]-pn[3], dy = pj[4]-pn[4], dz = pj[5]-pn[5];
        float d = sqrtf(dx*dx + dy*dy + dz*dz + 1e-6f);
        float inv = 1.f/(d + 1e-6f);
        float ux = dx*inv, uy = dy*inv, uz = dz*inv;
        float feats[40];
        #pragma unroll
        for (int bb = 0; bb < 16; ++bb) {                    // rbf: centers 22*i/15, 1/(2*1.375^2)
            float e = d - (22.f/15.f)*bb;
            feats[bb] = __expf(-e*e*0.264462809917f);
        }
        #pragma unroll
        for (int bb = 0; bb < 3; ++bb)                       // local_dir[b] = e_b . unit
            feats[16+bb] = Rn[bb]*ux + Rn[3+bb]*uy + Rn[6+bb]*uz;
        #pragma unroll
        for (int bb = 0; bb < 3; ++bb)                       // rel_rot[b][c] = e_b(n).e_c(j)
            #pragma unroll
            for (int cc = 0; cc < 3; ++cc)
                feats[19+bb*3+cc] = Rn[bb]*Rj[cc] + Rn[3+bb]*Rj[3+cc] + Rn[6+bb]*Rj[6+cc];
        #pragma unroll
        for (int aa = 0; aa < 4; ++aa) {                     // local_vec[A][b] = e_b(n).(pos[j][A]-t[n])
            float vx = pj[aa*3+0]-pn[3], vy = pj[aa*3+1]-pn[4], vz = pj[aa*3+2]-pn[5];
            #pragma unroll
            for (int bb = 0; bb < 3; ++bb)
                feats[28+aa*3+bb] = Rn[bb]*vx + Rn[3+bb]*vy + Rn[6+bb]*vz;
        }
        char* fb = smem + FEATS_OFF + t*128;
        const int rx = (t & 7) << 4;
        #pragma unroll
        for (int f = 0; f < 64; ++f) {
            unsigned short hv = (f < 40) ? f2bf(feats[f]) : (unsigned short)0;
            *(unsigned short*)(fb + ((2*f) ^ rx)) = hv;
        }
        int same = (chain[n]==chain[j]) & (batch[n]==batch[j]);
        int rel = resi[j] - resi[n];
        rel = (rel < -32 ? -32 : (rel > 32 ? 32 : rel)) + 32;
        ((int*)(smem + META_OFF))[t] = same ? (rel + 1) : 0;
    } else {
        const float4* src = (const float4*)wft;
        float4* dst = (float4*)(smem + WFT_OFF);
        for (int c = t - 64; c < 1024; c += 192) dst[c] = src[c];
    }
    __syncthreads();

    const int lane = t & 63;
    const int wid  = t >> 6;
    const int wr   = wid >> 1;       // 0..1 : 32-row strip
    const int wc   = wid & 1;        // 0..1 : 64-col strip
    const int lrow = lane & 15;
    const int lk   = lane >> 4;

    // ---------------- feature GEMM: feats[64x64] @ Wf[64x128] -> pair0
    {
        f32x4 accF[2][4];
        #pragma unroll
        for (int mi=0;mi<2;mi++) {
            #pragma unroll
            for (int ni=0;ni<4;ni++) accF[mi][ni] = (f32x4){0.f,0.f,0.f,0.f};
        }
        #pragma unroll
        for (int ks = 0; ks < 2; ++ks) {
            const int kb = 2*(8*lk + 32*ks);
            bf16x8 a[2], b[4];
            #pragma unroll
            for (int mi=0;mi<2;mi++) {
                int r = wr*32 + mi*16 + lrow;
                a[mi] = *(const bf16x8*)(smem + FEATS_OFF + r*128 + (kb ^ ((r&7)<<4)));
            }
            #pragma unroll
            for (int ni=0;ni<4;ni++) {
                int c = wc*64 + ni*16 + lrow;
                b[ni] = *(const bf16x8*)(smem + WFT_OFF + c*128 + (kb ^ ((c&7)<<4)));
            }
            #pragma unroll
            for (int mi=0;mi<2;mi++) {
                #pragma unroll
                for (int ni=0;ni<4;ni++) accF[mi][ni] = MFMA16(a[mi], b[ni], accF[mi][ni]);
            }
        }
        float* p0 = (float*)smem;
        #pragma unroll
        for (int mi=0;mi<2;mi++) {
            #pragma unroll
            for (int ni=0;ni<4;ni++) {
                #pragma unroll
                for (int i=0;i<4;i++) {
                    int r = wr*32 + mi*16 + lk*4 + i;
                    int c = wc*64 + ni*16 + lrow;
                    p0[r*132 + c] = accF[mi][ni][i];
                }
            }
        }
    }
    __syncthreads();

    // ---------------- W_rel add + LayerNorm -> X (bf16, swizzled)
    {
        const float* p0 = (const float*)smem;
        const int r = t >> 2, q = t & 3;
        const int mr = ((const int*)(smem + META_OFF))[r];
        const float* wrel = W_rel + (mr ? (mr - 1) : 0) * 128;
        const float sm = mr ? 1.f : 0.f;
        float v[32]; float s = 0.f, ss = 0.f;
        #pragma unroll
        for (int i = 0; i < 32; ++i) {
            int p = q + 4*i;
            float x = p0[r*132 + p] + sm * wrel[p];
            v[i] = x; s += x; ss += x*x;
        }
        s  += __shfl_xor(s, 1);  s  += __shfl_xor(s, 2);
        ss += __shfl_xor(ss, 1); ss += __shfl_xor(ss, 2);
        float mu  = s * 0.0078125f;
        float var = ss * 0.0078125f - mu*mu;
        float rstd = rsqrtf(var + 1e-5f);
        __syncthreads();                       // all pair0 reads complete
        const int rx = (r & 7) << 4;
        #pragma unroll
        for (int i = 0; i < 32; ++i) {
            int p = q + 4*i;
            float xv = (v[i] - mu) * rstd * ln_scale[p] + ln_bias[p];
            *(unsigned short*)(smem + r*256 + ((2*p) ^ rx)) = f2bf(xv);
        }
    }

    // ---------------- MLP: x@W1 -> gelu -> h@W2, K split in 2 halves of 128
    f32x4 acc2[2][4];
    #pragma unroll
    for (int mi=0;mi<2;mi++) {
        #pragma unroll
        for (int ni=0;ni<4;ni++) acc2[mi][ni] = (f32x4){0.f,0.f,0.f,0.f};
    }
    char* Wb = smem + WB_OFF;
    char* Hb = smem + HB_OFF;

    for (int half = 0; half < 2; ++half) {
        __syncthreads();
        {   // stage W1 half (pre-swizzled in global -> linear copy)
            const float4* src = (const float4*)w1t + half*2048;
            float4* dst = (float4*)Wb;
            for (int c = t; c < 2048; c += 256) dst[c] = src[c];
        }
        __syncthreads();

        f32x4 acc1[2][4];
        #pragma unroll
        for (int mi=0;mi<2;mi++) {
            #pragma unroll
            for (int ni=0;ni<4;ni++) acc1[mi][ni] = (f32x4){0.f,0.f,0.f,0.f};
        }
        #pragma unroll
        for (int ks = 0; ks < 4; ++ks) {
            const int kb = 2*(8*lk + 32*ks);
            bf16x8 a[2], b[4];
            #pragma unroll
            for (int mi=0;mi<2;mi++) {
                int r = wr*32 + mi*16 + lrow;
                a[mi] = *(const bf16x8*)(smem + r*256 + (kb ^ ((r&7)<<4)));
            }
            #pragma unroll
            for (int ni=0;ni<4;ni++) {
                int c = wc*64 + ni*16 + lrow;
                b[ni] = *(const bf16x8*)(Wb + c*256 + (kb ^ ((c&7)<<4)));
            }
            #pragma unroll
            for (int mi=0;mi<2;mi++) {
                #pragma unroll
                for (int ni=0;ni<4;ni++) acc1[mi][ni] = MFMA16(a[mi], b[ni], acc1[mi][ni]);
            }
        }
        // bias + gelu(tanh approx, as jax.nn.gelu) -> H bf16 swizzled
        #pragma unroll
        for (int ni=0;ni<4;ni++) {
            int c = wc*64 + ni*16 + lrow;
            float bias = b1[half*128 + c];
            #pragma unroll
            for (int mi=0;mi<2;mi++) {
                #pragma unroll
                for (int i=0;i<4;i++) {
                    int r = wr*32 + mi*16 + lk*4 + i;
                    float x = acc1[mi][ni][i] + bias;
                    float yy = 0.7978845608028654f * (x + 0.044715f*x*x*x);
                    float th = 1.f - 2.f/(__expf(2.f*yy) + 1.f);
                    float gv = 0.5f * x * (1.f + th);
                    *(unsigned short*)(Hb + r*256 + ((2*c) ^ ((r&7)<<4))) = f2bf(gv);
                }
            }
        }
        __syncthreads();
        {   // stage W2 half
            const float4* src = (const float4*)w2t + half*2048;
            float4* dst = (float4*)Wb;
            for (int c = t; c < 2048; c += 256) dst[c] = src[c];
        }
        __syncthreads();
        #pragma unroll
        for (int ks = 0; ks < 4; ++ks) {
            const int kb = 2*(8*lk + 32*ks);
            bf16x8 a[2], b[4];
            #pragma unroll
            for (int mi=0;mi<2;mi++) {
                int r = wr*32 + mi*16 + lrow;
                a[mi] = *(const bf16x8*)(Hb + r*256 + (kb ^ ((r&7)<<4)));
            }
            #pragma unroll
            for (int ni=0;ni<4;ni++) {
                int c = wc*64 + ni*16 + lrow;
                b[ni] = *(const bf16x8*)(Wb + c*256 + (kb ^ ((c&7)<<4)));
            }
            #pragma unroll
            for (int mi=0;mi<2;mi++) {
                #pragma unroll
                for (int ni=0;ni<4;ni++) acc2[mi][ni] = MFMA16(a[mi], b[ni], acc2[mi][ni]);
            }
        }
    }

    // ---------------- epilogue: + b2, store fp32
    #pragma unroll
    for (int ni=0;ni<4;ni++) {
        int c = wc*64 + ni*16 + lrow;
        float bias = b2[c];
        #pragma unroll
        for (int mi=0;mi<2;mi++) {
            #pragma unroll
            for (int i=0;i<4;i++) {
                int r = wr*32 + mi*16 + lk*4 + i;
                size_t gidx = (size_t)(row0 + r)*128 + c;
                out[gidx] = acc2[mi][ni][i] + bias;
            }
        }
    }
}

extern "C" void kernel_launch(void* const* d_in, const int* in_sizes, int n_in,
                              void* d_out, int out_size, void* d_ws, size_t ws_size,
                              hipStream_t stream) {
    const float* pos      = (const float*)d_in[0];
    const int*   nbr      = (const int*)d_in[1];
    const int*   resi     = (const int*)d_in[2];
    const int*   chain    = (const int*)d_in[3];
    const int*   batch    = (const int*)d_in[4];
    const float* mask     = (const float*)d_in[5];
    const float* W_rel    = (const float*)d_in[6];
    const float* W_dist   = (const float*)d_in[7];
    const float* W_dir    = (const float*)d_in[8];
    const float* W_rot    = (const float*)d_in[9];
    const float* W_vec    = (const float*)d_in[10];
    const float* ln_scale = (const float*)d_in[11];
    const float* ln_bias  = (const float*)d_in[12];
    const float* W1       = (const float*)d_in[13];
    const float* b1       = (const float*)d_in[14];
    const float* W2       = (const float*)d_in[15];
    const float* b2       = (const float*)d_in[16];

    unsigned short* w1t = (unsigned short*)d_ws;          // 64 KB
    unsigned short* w2t = w1t + 32768;                    // 64 KB
    unsigned short* wft = w2t + 32768;                    // 16 KB
    float* out  = (float*)d_out;
    float* outm = out + (size_t)NK * 128;

    sd_prep_weights<<<288, 256, 0, stream>>>(W1, W2, W_dist, W_dir, W_rot, W_vec, w1t, w2t, wft);
    sd_mask_kernel<<<NK/256, 256, 0, stream>>>(nbr, mask, outm);
    sd_fused_kernel<<<NK/64, 256, 0, stream>>>(pos, nbr, resi, chain, batch, W_rel,
                                               ln_scale, ln_bias, b1, b2, w1t, w2t, wft, out);
}

// Round 4
// 484.128 us; speedup vs baseline: 1.0788x; 1.0788x over previous
//
#include <hip/hip_runtime.h>
#include <hip/hip_bf16.h>

#define N_NODES 32768
#define NK      1048576      // N*K edges

typedef __bf16 bf16x8 __attribute__((ext_vector_type(8)));
typedef float  f32x4  __attribute__((ext_vector_type(4)));
typedef short  short4v __attribute__((ext_vector_type(4)));

// LDS layout (bytes), 50,432 total -> 3 blocks/CU:
//  X   region @ 0      (16 KB): wft [128p][64k] swz during phase F; X [64r][128p] swz after LN
//  W   region @ 16384  (32 KB): feats [64r][64k] swz during phase F (first 8 KB);
//                               then W1-half / W2-half [128][128] swz; epilogue exchange buffer
//  aux region @ 49152  : meta int[64] (256 B), partS [64][2] f32 (512 B), partSS (512 B)
#define XOFF   0
#define WOFF   16384
#define AUXM   49152
#define AUXS   49408
#define AUXSS  49920
#define SMEM_BYTES 50432

static __device__ __forceinline__ unsigned short f2bf(float f) {
    union { float f; unsigned int u; } v; v.f = f;
    unsigned int u = v.u;
    return (unsigned short)((u + 0x7fffu + ((u >> 16) & 1u)) >> 16);   // RNE
}

static __device__ __forceinline__ void glds16(char* lds, const char* g) {
    __builtin_amdgcn_global_load_lds((const __attribute__((address_space(1))) unsigned int*)g,
                                     (__attribute__((address_space(3))) unsigned int*)lds,
                                     16, 0, 0);
}

#define WAIT_VM0()  asm volatile("s_waitcnt vmcnt(0)" ::: "memory")
#define WAIT_LGKM() asm volatile("s_waitcnt lgkmcnt(0)" ::: "memory")
#define WAIT_ALL()  asm volatile("s_waitcnt vmcnt(0) lgkmcnt(0)" ::: "memory")
#define BAR()       __builtin_amdgcn_s_barrier()

// R[a*3+b] = e_{b}[a]  (columns e1,e2,e3)
static __device__ __forceinline__ void make_frame(const float* __restrict__ p, float* __restrict__ R) {
    float v1x = p[6]-p[3], v1y = p[7]-p[4], v1z = p[8]-p[5];
    float v2x = p[0]-p[3], v2y = p[1]-p[4], v2z = p[2]-p[5];
    float i1 = 1.f/(sqrtf(v1x*v1x+v1y*v1y+v1z*v1z)+1e-6f);
    float e1x=v1x*i1, e1y=v1y*i1, e1z=v1z*i1;
    float dt = v2x*e1x+v2y*e1y+v2z*e1z;
    float u2x=v2x-dt*e1x, u2y=v2y-dt*e1y, u2z=v2z-dt*e1z;
    float i2 = 1.f/(sqrtf(u2x*u2x+u2y*u2y+u2z*u2z)+1e-6f);
    float e2x=u2x*i2, e2y=u2y*i2, e2z=u2z*i2;
    float e3x = e1y*e2z - e1z*e2y;
    float e3y = e1z*e2x - e1x*e2z;
    float e3z = e1x*e2y - e1y*e2x;
    R[0]=e1x; R[1]=e2x; R[2]=e3x;
    R[3]=e1y; R[4]=e2y; R[5]=e3y;
    R[6]=e1z; R[7]=e2z; R[8]=e3z;
}

// ---- prep: bf16-convert + transpose + pre-swizzle weights into ws ----
// w1t: W1[p][h] at byte half*32768 + hl*256 + ((2p)^((hl&7)<<4)),  h=half*128+hl   [A-frags, rows=h]
// w2t: W2[h][p] at byte half*32768 + p*256  + ((2hl)^((p&7)<<4))                   [B-frags, rows=p]
// wft: Wf[f][p] at byte p*128 + ((2f)^((p&7)<<4)),  f<40 real else 0
__global__ void sd_prep_weights(const float* __restrict__ W1, const float* __restrict__ W2,
                                const float* __restrict__ Wd, const float* __restrict__ Wdir,
                                const float* __restrict__ Wrot, const float* __restrict__ Wvec,
                                unsigned short* __restrict__ w1t, unsigned short* __restrict__ w2t,
                                unsigned short* __restrict__ wft) {
    int i = blockIdx.x*256 + threadIdx.x;
    if (i < 32768) {
        int h = i >> 7, p = i & 127;
        int half = h >> 7, hl = h & 127;
        int byteoff = half*32768 + hl*256 + ((2*p) ^ ((hl&7)<<4));
        w1t[byteoff>>1] = f2bf(W1[p*256 + h]);
    } else if (i < 65536) {
        int idx = i - 32768;
        int p = idx >> 8, h = idx & 255;
        int half = h >> 7, hl = h & 127;
        int byteoff = half*32768 + p*256 + ((2*hl) ^ ((p&7)<<4));
        w2t[byteoff>>1] = f2bf(W2[h*128 + p]);
    } else if (i < 73728) {
        int idx = i - 65536;
        int p = idx >> 6, f = idx & 63;
        float v = 0.f;
        if (f < 16)      v = Wd[f*128+p];
        else if (f < 19) v = Wdir[(f-16)*128+p];
        else if (f < 28) v = Wrot[(f-19)*128+p];
        else if (f < 40) v = Wvec[(f-28)*128+p];
        int byteoff = p*128 + ((2*f) ^ ((p&7)<<4));
        wft[byteoff>>1] = f2bf(v);
    }
}

__global__ void sd_mask_kernel(const int* __restrict__ nbr, const float* __restrict__ mask,
                               float* __restrict__ outm) {
    int g = blockIdx.x*256 + threadIdx.x;
    if (g >= NK) return;
    int j = nbr[g];
    int n = g >> 5;
    float pm = mask[n] * mask[j & (N_NODES-1)] * ((j != -1) ? 1.f : 0.f);
    outm[g] = pm;
}

#define MFMA32(a,b,c) __builtin_amdgcn_mfma_f32_16x16x32_bf16((a),(b),(c),0,0,0)
#define MFMA16(a,b,c) __builtin_amdgcn_mfma_f32_16x16x16bf16_1k((a),(b),(c),0,0,0)

__global__ __launch_bounds__(256, 3) void sd_fused_kernel(
    const float* __restrict__ pos, const int* __restrict__ nbr,
    const int* __restrict__ resi, const int* __restrict__ chain,
    const int* __restrict__ batch,
    const float* __restrict__ W_rel, const float* __restrict__ ln_scale,
    const float* __restrict__ ln_bias, const float* __restrict__ b1,
    const float* __restrict__ b2,
    const unsigned short* __restrict__ w1t, const unsigned short* __restrict__ w2t,
    const unsigned short* __restrict__ wft,
    float* __restrict__ out)
{
    __shared__ __align__(16) char smem[SMEM_BYTES];
    const int t = threadIdx.x;
    const int lane = t & 63;
    const int wid  = t >> 6;
    const int wr   = wid >> 1;       // 0..1 : 64-h strip (per 128-h half)
    const int wc   = wid & 1;        // 0..1 : 32-edge strip
    const int lrow = lane & 15;
    const int lk   = lane >> 4;
    const int row0 = blockIdx.x * 64;

    // ---- issue wft -> X region (16 KB, pre-swizzled, linear copy) ----
    {
        const char* src = (const char*)wft + wid*4096 + lane*16;
        char* dst = smem + XOFF + wid*4096;
        #pragma unroll
        for (int k = 0; k < 4; ++k) glds16(dst + k*1024, src + k*1024);
    }

    // ---- phase F: per-edge features (wave 0), feats -> W region head, meta -> aux ----
    if (t < 64) {
        const int g = row0 + t;
        const int n = g >> 5;
        const int j = nbr[g] & (N_NODES - 1);
        float pn[12], pj[12];
        #pragma unroll
        for (int i = 0; i < 12; ++i) { pn[i] = pos[n*12+i]; pj[i] = pos[j*12+i]; }
        float Rn[9], Rj[9];
        make_frame(pn, Rn); make_frame(pj, Rj);
        float dx = pj[3]-pn[3], dy = pj[4]-pn[4], dz = pj[5]-pn[5];
        float d = sqrtf(dx*dx + dy*dy + dz*dz + 1e-6f);
        float inv = 1.f/(d + 1e-6f);
        float ux = dx*inv, uy = dy*inv, uz = dz*inv;
        float feats[40];
        #pragma unroll
        for (int bb = 0; bb < 16; ++bb) {
            float e = d - (22.f/15.f)*bb;
            feats[bb] = __expf(-e*e*0.264462809917f);
        }
        #pragma unroll
        for (int bb = 0; bb < 3; ++bb)
            feats[16+bb] = Rn[bb]*ux + Rn[3+bb]*uy + Rn[6+bb]*uz;
        #pragma unroll
        for (int bb = 0; bb < 3; ++bb)
            #pragma unroll
            for (int cc = 0; cc < 3; ++cc)
                feats[19+bb*3+cc] = Rn[bb]*Rj[cc] + Rn[3+bb]*Rj[3+cc] + Rn[6+bb]*Rj[6+cc];
        #pragma unroll
        for (int aa = 0; aa < 4; ++aa) {
            float vx = pj[aa*3+0]-pn[3], vy = pj[aa*3+1]-pn[4], vz = pj[aa*3+2]-pn[5];
            #pragma unroll
            for (int bb = 0; bb < 3; ++bb)
                feats[28+aa*3+bb] = Rn[bb]*vx + Rn[3+bb]*vy + Rn[6+bb]*vz;
        }
        char* fb = smem + WOFF + t*128;
        const int rx = (t & 7) << 4;
        #pragma unroll
        for (int f = 0; f < 64; ++f) {
            unsigned short hv = (f < 40) ? f2bf(feats[f]) : (unsigned short)0;
            *(unsigned short*)(fb + ((2*f) ^ rx)) = hv;
        }
        int same = (chain[n]==chain[j]) & (batch[n]==batch[j]);
        int rel = resi[j] - resi[n];
        rel = (rel < -32 ? -32 : (rel > 32 ? 32 : rel)) + 32;
        ((int*)(smem + AUXM))[t] = same ? (rel + 1) : 0;
    }
    WAIT_ALL(); BAR();                       // wft ready, feats+meta ready

    // ---- feature GEMM: C[edge][p] += feats @ Wf ----
    f32x4 accF[2][4];
    #pragma unroll
    for (int mi=0;mi<2;mi++)
        #pragma unroll
        for (int ni=0;ni<4;ni++) accF[mi][ni] = (f32x4){0.f,0.f,0.f,0.f};
    #pragma unroll
    for (int ks = 0; ks < 2; ++ks) {
        const int kb = 2*(8*lk + 32*ks);
        bf16x8 a[2], b[4];
        #pragma unroll
        for (int mi=0;mi<2;mi++) {
            int r = wr*32 + mi*16 + lrow;
            a[mi] = *(const bf16x8*)(smem + WOFF + r*128 + (kb ^ ((r&7)<<4)));
        }
        #pragma unroll
        for (int ni=0;ni<4;ni++) {
            int p = wc*64 + ni*16 + lrow;
            b[ni] = *(const bf16x8*)(smem + XOFF + p*128 + (kb ^ ((p&7)<<4)));
        }
        #pragma unroll
        for (int mi=0;mi<2;mi++)
            #pragma unroll
            for (int ni=0;ni<4;ni++) accF[mi][ni] = MFMA32(a[mi], b[ni], accF[mi][ni]);
    }
    WAIT_LGKM(); BAR();                      // feats + wft consumed -> both regions free

    // ---- issue W1 half0 -> W region (32 KB) ----
    {
        const char* src = (const char*)w1t + wid*8192 + lane*16;
        char* dst = smem + WOFF + wid*8192;
        #pragma unroll
        for (int k = 0; k < 8; ++k) glds16(dst + k*1024, src + k*1024);
    }

    // ---- register LayerNorm (W_rel add + mean/var via shfl + aux partials) ----
    #pragma unroll
    for (int mi=0;mi<2;mi++) {
        #pragma unroll
        for (int i=0;i<4;i++) {
            int r = wr*32 + mi*16 + lk*4 + i;
            int mt = ((const int*)(smem + AUXM))[r];
            const float* wrel = W_rel + (mt > 0 ? (mt-1)*128 : 0);
            float sv = (mt > 0) ? 1.f : 0.f;
            float s = 0.f, ss = 0.f;
            #pragma unroll
            for (int ni=0;ni<4;ni++) {
                int p = wc*64 + ni*16 + lrow;
                float x = accF[mi][ni][i] + sv * wrel[p];
                accF[mi][ni][i] = x;
                s += x; ss += x*x;
            }
            s += __shfl_xor(s,1); s += __shfl_xor(s,2); s += __shfl_xor(s,4); s += __shfl_xor(s,8);
            ss += __shfl_xor(ss,1); ss += __shfl_xor(ss,2); ss += __shfl_xor(ss,4); ss += __shfl_xor(ss,8);
            if (lrow == 0) {
                ((float*)(smem + AUXS ))[r*2 + wc] = s;
                ((float*)(smem + AUXSS))[r*2 + wc] = ss;
            }
        }
    }
    WAIT_LGKM(); BAR();                      // partials visible
    {
        float lnS[4], lnB[4];
        #pragma unroll
        for (int ni=0;ni<4;ni++) {
            int p = wc*64 + ni*16 + lrow;
            lnS[ni] = ln_scale[p]; lnB[ni] = ln_bias[p];
        }
        const float* pS  = (const float*)(smem + AUXS);
        const float* pSS = (const float*)(smem + AUXSS);
        #pragma unroll
        for (int mi=0;mi<2;mi++) {
            #pragma unroll
            for (int i=0;i<4;i++) {
                int r = wr*32 + mi*16 + lk*4 + i;
                float s  = pS [r*2] + pS [r*2+1];
                float ss = pSS[r*2] + pSS[r*2+1];
                float mu  = s * 0.0078125f;
                float var = ss * 0.0078125f - mu*mu;
                float rstd = rsqrtf(var + 1e-5f);
                int rx = (r&7) << 4;
                #pragma unroll
                for (int ni=0;ni<4;ni++) {
                    int p = wc*64 + ni*16 + lrow;
                    float xv = (accF[mi][ni][i] - mu) * rstd * lnS[ni] + lnB[ni];
                    *(unsigned short*)(smem + XOFF + r*256 + ((2*p) ^ rx)) = f2bf(xv);
                }
            }
        }
    }
    WAIT_ALL(); BAR();                       // X ready + W1h0 ready

    // ---- MLP: swapped GEMM1 (C1[h][edge]) -> in-reg gelu/pack -> GEMM2 via 16x16x16 ----
    // Per half of 128 h: wave handles 64 h (wr strip) x 32 edges (wc strip).
    f32x4 acc2[2][8];
    #pragma unroll
    for (int ni=0;ni<2;ni++)
        #pragma unroll
        for (int pb=0;pb<8;pb++) acc2[ni][pb] = (f32x4){0.f,0.f,0.f,0.f};

    #pragma unroll
    for (int half = 0; half < 2; ++half) {
        // GEMM1: A = W1h rows (h: wr*64 .. wr*64+64), B = X cols (edges). 64h x 32e per wave.
        f32x4 acc1[4][2];
        #pragma unroll
        for (int mi=0;mi<4;mi++)
            #pragma unroll
            for (int ni=0;ni<2;ni++) acc1[mi][ni] = (f32x4){0.f,0.f,0.f,0.f};
        #pragma unroll
        for (int ks = 0; ks < 4; ++ks) {
            const int kb = 2*(8*lk + 32*ks);
            bf16x8 a[4], b[2];
            #pragma unroll
            for (int mi=0;mi<4;mi++) {
                int hh = wr*64 + mi*16 + lrow;
                a[mi] = *(const bf16x8*)(smem + WOFF + hh*256 + (kb ^ ((hh&7)<<4)));
            }
            #pragma unroll
            for (int ni=0;ni<2;ni++) {
                int e = wc*32 + ni*16 + lrow;
                b[ni] = *(const bf16x8*)(smem + XOFF + e*256 + (kb ^ ((e&7)<<4)));
            }
            #pragma unroll
            for (int mi=0;mi<4;mi++)
                #pragma unroll
                for (int ni=0;ni<2;ni++) acc1[mi][ni] = MFMA32(a[mi], b[ni], acc1[mi][ni]);
        }
        WAIT_LGKM(); BAR();                  // W region free (all waves done reading W1h)

        // issue W2[half] -> W region; gelu+pack overlaps the flight
        {
            const char* src = (const char*)w2t + half*32768 + wid*8192 + lane*16;
            char* dst = smem + WOFF + wid*8192;
            #pragma unroll
            for (int k = 0; k < 8; ++k) glds16(dst + k*1024, src + k*1024);
        }
        short4v pa[4][2];
        #pragma unroll
        for (int mi=0;mi<4;mi++) {
            #pragma unroll
            for (int i=0;i<4;i++) {
                int hl = half*128 + wr*64 + mi*16 + 4*lk + i;
                float bv = b1[hl];
                #pragma unroll
                for (int ni=0;ni<2;ni++) {
                    float x = acc1[mi][ni][i] + bv;
                    float tt = x * (1.f + 0.044715f*x*x);
                    float e  = __expf(-1.59576912f * tt);
                    float gv = x / (1.f + e);            // == 0.5x(1+tanh(0.79788456*tt))
                    pa[mi][ni][i] = (short)f2bf(gv);
                }
            }
        }
        WAIT_VM0(); BAR();                   // W2h ready

        // GEMM2: A = pa (edges x 16h chunks), B = W2 frags; acc2[edges][p]
        #pragma unroll
        for (int ni=0;ni<2;ni++) {
            #pragma unroll
            for (int pb=0;pb<8;pb++) {
                int p = pb*16 + lrow;
                #pragma unroll
                for (int mi=0;mi<4;mi++) {
                    int hh2 = wr*64 + mi*16 + 4*lk;
                    short4v wf = *(const short4v*)(smem + WOFF + p*256 + ((2*hh2) ^ ((p&7)<<4)));
                    acc2[ni][pb] = MFMA16(pa[mi][ni], wf, acc2[ni][pb]);
                }
            }
        }
        WAIT_LGKM(); BAR();                  // W region free

        if (half == 0) {
            const char* src = (const char*)w1t + 32768 + wid*8192 + lane*16;
            char* dst = smem + WOFF + wid*8192;
            #pragma unroll
            for (int k = 0; k < 8; ++k) glds16(dst + k*1024, src + k*1024);
            WAIT_VM0(); BAR();               // W1h1 ready
        }
    }

    // ---- epilogue: cross-wave h-partial reduce (wr pairs), +b2, fp32 store ----
    if (wr == 1) {
        #pragma unroll
        for (int ni=0;ni<2;ni++)
            #pragma unroll
            for (int pb=0;pb<8;pb++)
                *(f32x4*)(smem + WOFF + wc*16384 + (ni*8+pb)*1024 + lane*16) = acc2[ni][pb];
    }
    WAIT_LGKM(); BAR();
    if (wr == 0) {
        #pragma unroll
        for (int ni=0;ni<2;ni++) {
            #pragma unroll
            for (int pb=0;pb<8;pb++) {
                f32x4 part = *(const f32x4*)(smem + WOFF + wc*16384 + (ni*8+pb)*1024 + lane*16);
                int p = pb*16 + lrow;
                float bb = b2[p];
                #pragma unroll
                for (int e=0;e<4;e++) {
                    int row = wc*32 + ni*16 + 4*lk + e;
                    out[(size_t)(row0 + row)*128 + p] = acc2[ni][pb][e] + part[e] + bb;
                }
            }
        }
    }
}

extern "C" void kernel_launch(void* const* d_in, const int* in_sizes, int n_in,
                              void* d_out, int out_size, void* d_ws, size_t ws_size,
                              hipStream_t stream) {
    const float* pos      = (const float*)d_in[0];
    const int*   nbr      = (const int*)d_in[1];
    const int*   resi     = (const int*)d_in[2];
    const int*   chain    = (const int*)d_in[3];
    const int*   batch    = (const int*)d_in[4];
    const float* mask     = (const float*)d_in[5];
    const float* W_rel    = (const float*)d_in[6];
    const float* W_dist   = (const float*)d_in[7];
    const float* W_dir    = (const float*)d_in[8];
    const float* W_rot    = (const float*)d_in[9];
    const float* W_vec    = (const float*)d_in[10];
    const float* ln_scale = (const float*)d_in[11];
    const float* ln_bias  = (const float*)d_in[12];
    const float* W1       = (const float*)d_in[13];
    const float* b1       = (const float*)d_in[14];
    const float* W2       = (const float*)d_in[15];
    const float* b2       = (const float*)d_in[16];

    unsigned short* w1t = (unsigned short*)d_ws;          // 64 KB
    unsigned short* w2t = w1t + 32768;                    // 64 KB
    unsigned short* wft = w2t + 32768;                    // 16 KB
    float* out  = (float*)d_out;
    float* outm = out + (size_t)NK * 128;

    sd_prep_weights<<<288, 256, 0, stream>>>(W1, W2, W_dist, W_dir, W_rot, W_vec, w1t, w2t, wft);
    sd_mask_kernel<<<NK/256, 256, 0, stream>>>(nbr, mask, outm);
    sd_fused_kernel<<<NK/64, 256, 0, stream>>>(pos, nbr, resi, chain, batch, W_rel,
                                               ln_scale, ln_bias, b1, b2, w1t, w2t, wft, out);
}

// Round 7
// 450.662 us; speedup vs baseline: 1.1589x; 1.0743x over previous
//
#include <hip/hip_runtime.h>
#include <hip/hip_bf16.h>

#define N_NODES 32768
#define NK      1048576      // N*K edges

typedef __bf16 bf16x8 __attribute__((ext_vector_type(8)));
typedef float  f32x4  __attribute__((ext_vector_type(4)));
typedef short  short4v __attribute__((ext_vector_type(4)));
typedef int    int4v  __attribute__((ext_vector_type(4)));
typedef int    int2v  __attribute__((ext_vector_type(2)));

#define WAIT_LGKM() asm volatile("s_waitcnt lgkmcnt(0)" ::: "memory")

static __device__ __forceinline__ unsigned fbits(float f) {
    union { float f; unsigned u; } v; v.f = f; return v.u;
}
static __device__ __forceinline__ unsigned short f2bf(float f) {
    unsigned u = fbits(f);
    return (unsigned short)((u + 0x7fffu + ((u >> 16) & 1u)) >> 16);   // RNE
}

// R[a*3+b] = e_{b}[a]  (columns e1,e2,e3)
static __device__ __forceinline__ void make_frame(const float* __restrict__ p, float* __restrict__ R) {
    float v1x = p[6]-p[3], v1y = p[7]-p[4], v1z = p[8]-p[5];
    float v2x = p[0]-p[3], v2y = p[1]-p[4], v2z = p[2]-p[5];
    float i1 = 1.f/(sqrtf(v1x*v1x+v1y*v1y+v1z*v1z)+1e-6f);
    float e1x=v1x*i1, e1y=v1y*i1, e1z=v1z*i1;
    float dt = v2x*e1x+v2y*e1y+v2z*e1z;
    float u2x=v2x-dt*e1x, u2y=v2y-dt*e1y, u2z=v2z-dt*e1z;
    float i2 = 1.f/(sqrtf(u2x*u2x+u2y*u2y+u2z*u2z)+1e-6f);
    float e2x=u2x*i2, e2y=u2y*i2, e2z=u2z*i2;
    float e3x = e1y*e2z - e1z*e2y;
    float e3y = e1z*e2x - e1x*e2z;
    float e3z = e1x*e2y - e1y*e2x;
    R[0]=e1x; R[1]=e2x; R[2]=e3x;
    R[3]=e1y; R[4]=e2y; R[5]=e3y;
    R[6]=e1z; R[7]=e2z; R[8]=e3z;
}

// ---------------- prep: pack weights into frag-linear bf16 layouts (144 KB total) ----------------
// wftp: feature-GEMM B-frags, K=64. frag(pb,ks): f = 8*(lane>>4)+j+32*ks (<40 real, else 0),
//       p = pb*16+(lane&15).                                   [8192 shorts]
// w1p : GEMM1 A-frags, NATURAL k=p. frag(ht,ks): h = ht*16+(lane&15),
//       p = 8*(lane>>4)+j+32*ks; value = W1[p][h].             [32768 shorts]
// w2p : GEMM2 B-frags (16x16x16, kt-pairs). frag(pt,ktp): half = j>>2, jj = j&3,
//       h = (2*ktp+half)*16 + 4*(lane>>4)+jj, p = pt*16+(lane&15); value = W2[h][p]. [32768 shorts]
__global__ void sd_prep_weights(const float* __restrict__ W1, const float* __restrict__ W2,
                                const float* __restrict__ Wd, const float* __restrict__ Wdir,
                                const float* __restrict__ Wrot, const float* __restrict__ Wvec,
                                unsigned short* __restrict__ wftp, unsigned short* __restrict__ w1p,
                                unsigned short* __restrict__ w2p) {
    int i = blockIdx.x*256 + threadIdx.x;
    if (i < 8192) {
        int fragid = i >> 9, lane = (i >> 3) & 63, j = i & 7;
        int pb = fragid >> 1, ks = fragid & 1;
        int f = 8*(lane>>4) + j + 32*ks;
        int p = pb*16 + (lane & 15);
        float v = 0.f;
        if (f < 16)       v = Wd[f*128+p];
        else if (f < 19)  v = Wdir[(f-16)*128+p];
        else if (f < 28)  v = Wrot[(f-19)*128+p];
        else if (f < 40)  v = Wvec[(f-28)*128+p];
        wftp[i] = f2bf(v);
    } else if (i < 40960) {
        int idx = i - 8192;
        int fragid = idx >> 9, lane = (idx >> 3) & 63, j = idx & 7;
        int ht = fragid >> 2, ks = fragid & 3;
        int h = ht*16 + (lane & 15);
        int p = 8*(lane>>4) + j + 32*ks;          // NATURAL order (no permutation)
        w1p[idx] = f2bf(W1[p*256 + h]);
    } else if (i < 73728) {
        int idx = i - 40960;
        int fragid = idx >> 9, lane = (idx >> 3) & 63, j = idx & 7;
        int pt = fragid >> 3, ktp = fragid & 7;
        int half = j >> 2, jj = j & 3;
        int h = (2*ktp + half)*16 + 4*(lane>>4) + jj;
        int p = pt*16 + (lane & 15);
        w2p[idx] = f2bf(W2[h*128 + p]);
    }
}

__global__ void sd_mask_kernel(const int* __restrict__ nbr, const float* __restrict__ mask,
                               float* __restrict__ outm) {
    int g = blockIdx.x*256 + threadIdx.x;
    if (g >= NK) return;
    int j = nbr[g];
    int n = g >> 5;
    float pm = mask[n] * mask[j & (N_NODES-1)] * ((j != -1) ? 1.f : 0.f);
    outm[g] = pm;
}

#define MFMA32(a,b,c) __builtin_amdgcn_mfma_f32_16x16x32_bf16((a),(b),(c),0,0,0)
#define MFMA16(a,b,c) __builtin_amdgcn_mfma_f32_16x16x16bf16_1k((a),(b),(c),0,0,0)

// 4 independent waves per block, 32 edges each. NO barriers anywhere.
// Per-wave LDS (12 KB): feats [32 rows x 128B, swz] @ 0 ; X [32 rows x 256B, swz] @ 4096.
__global__ __launch_bounds__(256, 3) void sd_fused_kernel(
    const float* __restrict__ pos, const int* __restrict__ nbr,
    const int* __restrict__ resi, const int* __restrict__ chain,
    const int* __restrict__ batch, const float* __restrict__ W_rel,
    const float* __restrict__ ln_scale, const float* __restrict__ ln_bias,
    const float* __restrict__ b1, const float* __restrict__ b2,
    const char* __restrict__ wftp_c, const char* __restrict__ w1p_c,
    const char* __restrict__ w2p_c,
    float* __restrict__ out)
{
    __shared__ __align__(16) char smem[49664];
    const int t    = threadIdx.x;
    const int lane = t & 63;
    const int wid  = t >> 6;
    const int lrow = lane & 15;
    const int lk   = lane >> 4;
    const int edge0 = blockIdx.x * 128 + wid * 32;
    char* Fv = smem + wid * 12288;             // feats region (4 KB)
    char* Xv = Fv + 4096;                      // X region (8 KB)
    int* meta = (int*)(smem + 49152 + wid*128);

    // ---- zero-fill feats region (tail f in [40,64) must be zero) ----
    {
        int4v z = (int4v){0,0,0,0};
        #pragma unroll
        for (int k = 0; k < 4; ++k) *(int4v*)(Fv + lane*64 + k*16) = z;
    }
    WAIT_LGKM();

    // ---- phase F: 2 lanes per edge ----
    {
        const int e   = lane >> 1;
        const int sub = lane & 1;
        const int g   = edge0 + e;
        const int n   = g >> 5;
        const int jn  = nbr[g] & (N_NODES - 1);
        float pn[12], pj[12];
        #pragma unroll
        for (int r = 0; r < 3; ++r) {
            f32x4 a = *(const f32x4*)(pos + n*12 + r*4);
            f32x4 b = *(const f32x4*)(pos + jn*12 + r*4);
            #pragma unroll
            for (int c = 0; c < 4; ++c) { pn[r*4+c] = a[c]; pj[r*4+c] = b[c]; }
        }
        float Rn[9], Rj[9];
        make_frame(pn, Rn); make_frame(pj, Rj);
        float dx = pj[3]-pn[3], dy = pj[4]-pn[4], dz = pj[5]-pn[5];
        float d = sqrtf(dx*dx + dy*dy + dz*dz + 1e-6f);
        float inv = 1.f/(d + 1e-6f);
        float ux = dx*inv, uy = dy*inv, uz = dz*inv;
        float feats[40];
        #pragma unroll
        for (int bb = 0; bb < 16; ++bb) {
            float ee = d - (22.f/15.f)*bb;
            feats[bb] = __expf(-ee*ee*0.264462809917f);
        }
        #pragma unroll
        for (int bb = 0; bb < 3; ++bb)
            feats[16+bb] = Rn[bb]*ux + Rn[3+bb]*uy + Rn[6+bb]*uz;
        #pragma unroll
        for (int bb = 0; bb < 3; ++bb)
            #pragma unroll
            for (int cc = 0; cc < 3; ++cc)
                feats[19+bb*3+cc] = Rn[bb]*Rj[cc] + Rn[3+bb]*Rj[3+cc] + Rn[6+bb]*Rj[6+cc];
        #pragma unroll
        for (int aa = 0; aa < 4; ++aa) {
            float vx = pj[aa*3+0]-pn[3], vy = pj[aa*3+1]-pn[4], vz = pj[aa*3+2]-pn[5];
            #pragma unroll
            for (int bb = 0; bb < 3; ++bb)
                feats[28+aa*3+bb] = Rn[bb]*vx + Rn[3+bb]*vy + Rn[6+bb]*vz;
        }
        char* fb = Fv + e*128;
        const int rx = (e & 7) << 4;
        if (!sub) {
            #pragma unroll
            for (int f = 0; f < 20; ++f)
                *(unsigned short*)(fb + ((2*f) ^ rx)) = f2bf(feats[f]);
        } else {
            #pragma unroll
            for (int f = 20; f < 40; ++f)
                *(unsigned short*)(fb + ((2*f) ^ rx)) = f2bf(feats[f]);
            int same = (chain[n]==chain[jn]) & (batch[n]==batch[jn]);
            int rel = resi[jn] - resi[n];
            rel = (rel < -32 ? -32 : (rel > 32 ? 32 : rel)) + 32;
            meta[e] = same ? (rel + 1) : 0;
        }
    }
    WAIT_LGKM();

    const int rxl = (lrow & 7) << 4;

    // ---- feature GEMM (K=64): accF[e][p] ----
    f32x4 accF[2][8];
    #pragma unroll
    for (int ni = 0; ni < 2; ++ni)
        #pragma unroll
        for (int pb = 0; pb < 8; ++pb) accF[ni][pb] = (f32x4){0.f,0.f,0.f,0.f};
    #pragma unroll
    for (int ks = 0; ks < 2; ++ks) {
        bf16x8 a0 = *(const bf16x8*)(Fv + lrow*128       + ((16*lk + 64*ks) ^ rxl));
        bf16x8 a1 = *(const bf16x8*)(Fv + (16+lrow)*128  + ((16*lk + 64*ks) ^ rxl));
        #pragma unroll
        for (int pb = 0; pb < 8; ++pb) {
            bf16x8 b = *(const bf16x8*)(wftp_c + ((pb*2 + ks)*64 + lane)*16);
            accF[0][pb] = MFMA32(a0, b, accF[0][pb]);
            accF[1][pb] = MFMA32(a1, b, accF[1][pb]);
        }
    }

    // ---- W_rel add (fp32) + LayerNorm (in-register) -> X bf16 NATURAL layout ----
    {
        float lnSv[8], lnBv[8];
        #pragma unroll
        for (int pb = 0; pb < 8; ++pb) {
            lnSv[pb] = ln_scale[pb*16 + lrow];
            lnBv[pb] = ln_bias [pb*16 + lrow];
        }
        #pragma unroll
        for (int ni = 0; ni < 2; ++ni) {
            #pragma unroll
            for (int i = 0; i < 4; ++i) {
                int er = ni*16 + 4*lk + i;
                int mt = meta[er];
                const float* wrel = W_rel + (mt > 0 ? (mt-1)*128 : 0);
                float sv = (mt > 0) ? 1.f : 0.f;
                float s = 0.f, ss = 0.f;
                #pragma unroll
                for (int pb = 0; pb < 8; ++pb) {
                    float x = accF[ni][pb][i] + sv * wrel[pb*16 + lrow];
                    accF[ni][pb][i] = x;
                    s += x; ss += x*x;
                }
                s  += __shfl_xor(s,1);  s  += __shfl_xor(s,2);  s  += __shfl_xor(s,4);  s  += __shfl_xor(s,8);
                ss += __shfl_xor(ss,1); ss += __shfl_xor(ss,2); ss += __shfl_xor(ss,4); ss += __shfl_xor(ss,8);
                float mu  = s * 0.0078125f;
                float var = ss * 0.0078125f - mu*mu;
                float rstd = rsqrtf(var + 1e-5f);
                char* xb = Xv + er*256;
                const int rx2 = (er & 7) << 4;
                #pragma unroll
                for (int pb = 0; pb < 8; ++pb) {
                    float xv = (accF[ni][pb][i] - mu) * rstd * lnSv[pb] + lnBv[pb];
                    *(unsigned short*)(xb + ((2*(pb*16 + lrow)) ^ rx2)) = f2bf(xv);
                }
            }
        }
    }
    WAIT_LGKM();

    // ---- X frags held in registers for the whole MLP (natural k=p order) ----
    bf16x8 bx[2][4];
    #pragma unroll
    for (int ni = 0; ni < 2; ++ni)
        #pragma unroll
        for (int ks = 0; ks < 4; ++ks)
            bx[ni][ks] = *(const bf16x8*)(Xv + (ni*16+lrow)*256 + ((16*lk + 64*ks) ^ rxl));

    // ---- MLP: 8 slices of 32 h. GEMM1 (swapped, C1[h][e]) -> gelu in-reg -> GEMM2 ----
    f32x4 acc2[2][8];
    #pragma unroll
    for (int ni = 0; ni < 2; ++ni)
        #pragma unroll
        for (int pt = 0; pt < 8; ++pt) acc2[ni][pt] = (f32x4){0.f,0.f,0.f,0.f};

    const float C2 = -2.30220797f;   // -2*sqrt(2/pi)*log2(e)
    #pragma unroll
    for (int hc = 0; hc < 8; ++hc) {
        f32x4 acc1[2][2];
        #pragma unroll
        for (int m = 0; m < 2; ++m)
            #pragma unroll
            for (int ni = 0; ni < 2; ++ni) acc1[m][ni] = (f32x4){0.f,0.f,0.f,0.f};
        #pragma unroll
        for (int ks = 0; ks < 4; ++ks) {
            bf16x8 a0 = *(const bf16x8*)(w1p_c + (((hc*2  )*4 + ks)*64 + lane)*16);
            bf16x8 a1 = *(const bf16x8*)(w1p_c + (((hc*2+1)*4 + ks)*64 + lane)*16);
            acc1[0][0] = MFMA32(a0, bx[0][ks], acc1[0][0]);
            acc1[0][1] = MFMA32(a0, bx[1][ks], acc1[0][1]);
            acc1[1][0] = MFMA32(a1, bx[0][ks], acc1[1][0]);
            acc1[1][1] = MFMA32(a1, bx[1][ks], acc1[1][1]);
        }
        f32x4 b1v[2];
        b1v[0] = *(const f32x4*)(b1 + hc*32      + 4*lk);
        b1v[1] = *(const f32x4*)(b1 + hc*32 + 16 + 4*lk);
        short4v pa[2][2];
        #pragma unroll
        for (int m = 0; m < 2; ++m) {
            #pragma unroll
            for (int ni = 0; ni < 2; ++ni) {
                #pragma unroll
                for (int i = 0; i < 4; ++i) {
                    float x  = acc1[m][ni][i] + b1v[m][i];
                    float tt = x * __builtin_fmaf(0.044715f, x*x, 1.0f);
                    float ex = __builtin_amdgcn_exp2f(C2 * tt);
                    pa[m][ni][i] = (short)f2bf(x / (1.0f + ex));
                }
            }
        }
        #pragma unroll
        for (int pt = 0; pt < 8; ++pt) {
            int4v w = *(const int4v*)(w2p_c + ((pt*8 + hc)*64 + lane)*16);
            short4v f0 = __builtin_bit_cast(short4v, (int2v){w[0], w[1]});
            short4v f1 = __builtin_bit_cast(short4v, (int2v){w[2], w[3]});
            acc2[0][pt] = MFMA16(pa[0][0], f0, acc2[0][pt]);
            acc2[1][pt] = MFMA16(pa[0][1], f0, acc2[1][pt]);
            acc2[0][pt] = MFMA16(pa[1][0], f1, acc2[0][pt]);
            acc2[1][pt] = MFMA16(pa[1][1], f1, acc2[1][pt]);
        }
    }

    // ---- epilogue: + b2, fp32 store ----
    float b2v[8];
    #pragma unroll
    for (int pt = 0; pt < 8; ++pt) b2v[pt] = b2[pt*16 + lrow];
    #pragma unroll
    for (int ni = 0; ni < 2; ++ni) {
        #pragma unroll
        for (int pt = 0; pt < 8; ++pt) {
            #pragma unroll
            for (int i = 0; i < 4; ++i) {
                int er = ni*16 + 4*lk + i;
                out[(size_t)(edge0 + er)*128 + pt*16 + lrow] = acc2[ni][pt][i] + b2v[pt];
            }
        }
    }
}

extern "C" void kernel_launch(void* const* d_in, const int* in_sizes, int n_in,
                              void* d_out, int out_size, void* d_ws, size_t ws_size,
                              hipStream_t stream) {
    const float* pos      = (const float*)d_in[0];
    const int*   nbr      = (const int*)d_in[1];
    const int*   resi     = (const int*)d_in[2];
    const int*   chain    = (const int*)d_in[3];
    const int*   batch    = (const int*)d_in[4];
    const float* mask     = (const float*)d_in[5];
    const float* W_rel    = (const float*)d_in[6];
    const float* W_dist   = (const float*)d_in[7];
    const float* W_dir    = (const float*)d_in[8];
    const float* W_rot    = (const float*)d_in[9];
    const float* W_vec    = (const float*)d_in[10];
    const float* ln_scale = (const float*)d_in[11];
    const float* ln_bias  = (const float*)d_in[12];
    const float* W1       = (const float*)d_in[13];
    const float* b1       = (const float*)d_in[14];
    const float* W2       = (const float*)d_in[15];
    const float* b2       = (const float*)d_in[16];

    unsigned short* wftp = (unsigned short*)d_ws;         // 16 KB
    unsigned short* w1p  = wftp + 8192;                   // 64 KB
    unsigned short* w2p  = w1p + 32768;                   // 64 KB  (total 144 KB, proven)
    float* out  = (float*)d_out;
    float* outm = out + (size_t)NK * 128;

    sd_prep_weights<<<288, 256, 0, stream>>>(W1, W2, W_dist, W_dir, W_rot, W_vec,
                                             wftp, w1p, w2p);
    sd_mask_kernel<<<NK/256, 256, 0, stream>>>(nbr, mask, outm);
    sd_fused_kernel<<<NK/128, 256, 0, stream>>>(pos, nbr, resi, chain, batch, W_rel,
                                                ln_scale, ln_bias, b1, b2,
                                                (const char*)wftp, (const char*)w1p,
                                                (const char*)w2p, out);
}

// Round 8
// 393.125 us; speedup vs baseline: 1.3285x; 1.1464x over previous
//
#include <hip/hip_runtime.h>
#include <hip/hip_bf16.h>

#define N_NODES 32768
#define NK      1048576      // N*K edges

typedef __bf16 bf16x8 __attribute__((ext_vector_type(8)));
typedef float  f32x4  __attribute__((ext_vector_type(4)));
typedef short  short8v __attribute__((ext_vector_type(8)));
typedef int    int4v  __attribute__((ext_vector_type(4)));

#define WAIT_LGKM() asm volatile("s_waitcnt lgkmcnt(0)" ::: "memory")

static __device__ __forceinline__ unsigned fbits(float f) {
    union { float f; unsigned u; } v; v.f = f; return v.u;
}
static __device__ __forceinline__ unsigned short f2bf(float f) {
    unsigned u = fbits(f);
    return (unsigned short)((u + 0x7fffu + ((u >> 16) & 1u)) >> 16);   // RNE (prep only)
}
static __device__ __forceinline__ unsigned short hwbf(float f) {      // HW RNE convert
    return __builtin_bit_cast(unsigned short, __float2bfloat16(f));
}

// DPP butterfly add over the 16-lane row (no DS pipe)
template<int CTRL>
static __device__ __forceinline__ float dpp_add(float v) {
    int sw = __builtin_amdgcn_update_dpp(0, __builtin_bit_cast(int, v), CTRL, 0xf, 0xf, true);
    return v + __builtin_bit_cast(float, sw);
}
static __device__ __forceinline__ float row16_sum(float v) {
    v = dpp_add<0xB1>(v);    // quad_perm(1,0,3,2)  : xor 1
    v = dpp_add<0x4E>(v);    // quad_perm(2,3,0,1)  : xor 2
    v = dpp_add<0x141>(v);   // row_half_mirror     : combines quads 0<->1
    v = dpp_add<0x140>(v);   // row_mirror          : combines halves
    return v;
}

// R[a*3+b] = e_{b}[a]  (columns e1,e2,e3)
static __device__ __forceinline__ void make_frame(const float* __restrict__ p, float* __restrict__ R) {
    float v1x = p[6]-p[3], v1y = p[7]-p[4], v1z = p[8]-p[5];
    float v2x = p[0]-p[3], v2y = p[1]-p[4], v2z = p[2]-p[5];
    float i1 = 1.f/(sqrtf(v1x*v1x+v1y*v1y+v1z*v1z)+1e-6f);
    float e1x=v1x*i1, e1y=v1y*i1, e1z=v1z*i1;
    float dt = v2x*e1x+v2y*e1y+v2z*e1z;
    float u2x=v2x-dt*e1x, u2y=v2y-dt*e1y, u2z=v2z-dt*e1z;
    float i2 = 1.f/(sqrtf(u2x*u2x+u2y*u2y+u2z*u2z)+1e-6f);
    float e2x=u2x*i2, e2y=u2y*i2, e2z=u2z*i2;
    float e3x = e1y*e2z - e1z*e2y;
    float e3y = e1z*e2x - e1x*e2z;
    float e3z = e1x*e2y - e1y*e2x;
    R[0]=e1x; R[1]=e2x; R[2]=e3x;
    R[3]=e1y; R[4]=e2y; R[5]=e3y;
    R[6]=e1z; R[7]=e2z; R[8]=e3z;
}

// ---------------- prep: pack weights into frag-linear bf16 layouts (144 KB total) ----------------
// wftp: feature-GEMM B-frags, K=64. frag(pb,ks): f = 8*(lane>>4)+j+32*ks (<40 real, else 0),
//       p = pb*16+(lane&15).                                   [8192 shorts]
// w1p : GEMM1 A-frags, natural k=p. frag(ht,ks): h = ht*16+(lane&15),
//       p = 8*(lane>>4)+j+32*ks; value = W1[p][h].             [32768 shorts]
// w2p : GEMM2 B-frags for K=32 MFMA with PERMUTED k-carriage matching the gelu A-frag:
//       frag(pt,hc): h = hc*32 + (j>>2)*16 + 4*(lane>>4) + (j&3), p = pt*16+(lane&15);
//       value = W2[h][p].                                      [32768 shorts]
__global__ void sd_prep_weights(const float* __restrict__ W1, const float* __restrict__ W2,
                                const float* __restrict__ Wd, const float* __restrict__ Wdir,
                                const float* __restrict__ Wrot, const float* __restrict__ Wvec,
                                unsigned short* __restrict__ wftp, unsigned short* __restrict__ w1p,
                                unsigned short* __restrict__ w2p) {
    int i = blockIdx.x*256 + threadIdx.x;
    if (i < 8192) {
        int fragid = i >> 9, lane = (i >> 3) & 63, j = i & 7;
        int pb = fragid >> 1, ks = fragid & 1;
        int f = 8*(lane>>4) + j + 32*ks;
        int p = pb*16 + (lane & 15);
        float v = 0.f;
        if (f < 16)       v = Wd[f*128+p];
        else if (f < 19)  v = Wdir[(f-16)*128+p];
        else if (f < 28)  v = Wrot[(f-19)*128+p];
        else if (f < 40)  v = Wvec[(f-28)*128+p];
        wftp[i] = f2bf(v);
    } else if (i < 40960) {
        int idx = i - 8192;
        int fragid = idx >> 9, lane = (idx >> 3) & 63, j = idx & 7;
        int ht = fragid >> 2, ks = fragid & 3;
        int h = ht*16 + (lane & 15);
        int p = 8*(lane>>4) + j + 32*ks;          // natural order
        w1p[idx] = f2bf(W1[p*256 + h]);
    } else if (i < 73728) {
        int idx = i - 40960;
        int fragid = idx >> 9, lane = (idx >> 3) & 63, j = idx & 7;
        int pt = fragid >> 3, hc = fragid & 7;
        int h = hc*32 + (j>>2)*16 + 4*(lane>>4) + (j&3);
        int p = pt*16 + (lane & 15);
        w2p[idx] = f2bf(W2[h*128 + p]);
    }
}

__global__ void sd_mask_kernel(const int* __restrict__ nbr, const float* __restrict__ mask,
                               float* __restrict__ outm) {
    int g = blockIdx.x*256 + threadIdx.x;
    if (g >= NK) return;
    int j = nbr[g];
    int n = g >> 5;
    float pm = mask[n] * mask[j & (N_NODES-1)] * ((j != -1) ? 1.f : 0.f);
    outm[g] = pm;
}

#define MFMA32(a,b,c) __builtin_amdgcn_mfma_f32_16x16x32_bf16((a),(b),(c),0,0,0)

// 4 independent waves per block, 32 edges each. NO barriers anywhere.
// Per-wave LDS (12 KB): feats [32 rows x 128B, swz] @ 0 ; X [32 rows x 256B, swz] @ 4096.
__global__ __launch_bounds__(256, 3) void sd_fused_kernel(
    const float* __restrict__ pos, const int* __restrict__ nbr,
    const int* __restrict__ resi, const int* __restrict__ chain,
    const int* __restrict__ batch, const float* __restrict__ W_rel,
    const float* __restrict__ ln_scale, const float* __restrict__ ln_bias,
    const float* __restrict__ b1, const float* __restrict__ b2,
    const char* __restrict__ wftp_c, const char* __restrict__ w1p_c,
    const char* __restrict__ w2p_c,
    float* __restrict__ out)
{
    __shared__ __align__(16) char smem[49664];
    const int t    = threadIdx.x;
    const int lane = t & 63;
    const int wid  = t >> 6;
    const int lrow = lane & 15;
    const int lk   = lane >> 4;
    const int edge0 = blockIdx.x * 128 + wid * 32;
    char* Fv = smem + wid * 12288;             // feats region (4 KB)
    char* Xv = Fv + 4096;                      // X region (8 KB)
    int* meta = (int*)(smem + 49152 + wid*128);

    // ---- zero-fill feats region (tail f in [40,64) must be zero) ----
    {
        int4v z = (int4v){0,0,0,0};
        #pragma unroll
        for (int k = 0; k < 4; ++k) *(int4v*)(Fv + lane*64 + k*16) = z;
    }
    WAIT_LGKM();

    // ---- phase F: 2 lanes per edge ----
    {
        const int e   = lane >> 1;
        const int sub = lane & 1;
        const int g   = edge0 + e;
        const int n   = g >> 5;
        const int jn  = nbr[g] & (N_NODES - 1);
        float pn[12], pj[12];
        #pragma unroll
        for (int r = 0; r < 3; ++r) {
            f32x4 a = *(const f32x4*)(pos + n*12 + r*4);
            f32x4 b = *(const f32x4*)(pos + jn*12 + r*4);
            #pragma unroll
            for (int c = 0; c < 4; ++c) { pn[r*4+c] = a[c]; pj[r*4+c] = b[c]; }
        }
        float Rn[9], Rj[9];
        make_frame(pn, Rn); make_frame(pj, Rj);
        float dx = pj[3]-pn[3], dy = pj[4]-pn[4], dz = pj[5]-pn[5];
        float d = sqrtf(dx*dx + dy*dy + dz*dz + 1e-6f);
        float inv = 1.f/(d + 1e-6f);
        float ux = dx*inv, uy = dy*inv, uz = dz*inv;
        float feats[40];
        #pragma unroll
        for (int bb = 0; bb < 16; ++bb) {
            float ee = d - (22.f/15.f)*bb;
            feats[bb] = __expf(-ee*ee*0.264462809917f);
        }
        #pragma unroll
        for (int bb = 0; bb < 3; ++bb)
            feats[16+bb] = Rn[bb]*ux + Rn[3+bb]*uy + Rn[6+bb]*uz;
        #pragma unroll
        for (int bb = 0; bb < 3; ++bb)
            #pragma unroll
            for (int cc = 0; cc < 3; ++cc)
                feats[19+bb*3+cc] = Rn[bb]*Rj[cc] + Rn[3+bb]*Rj[3+cc] + Rn[6+bb]*Rj[6+cc];
        #pragma unroll
        for (int aa = 0; aa < 4; ++aa) {
            float vx = pj[aa*3+0]-pn[3], vy = pj[aa*3+1]-pn[4], vz = pj[aa*3+2]-pn[5];
            #pragma unroll
            for (int bb = 0; bb < 3; ++bb)
                feats[28+aa*3+bb] = Rn[bb]*vx + Rn[3+bb]*vy + Rn[6+bb]*vz;
        }
        char* fb = Fv + e*128;
        const int rx = (e & 7) << 4;
        if (!sub) {
            #pragma unroll
            for (int f = 0; f < 20; ++f)
                *(unsigned short*)(fb + ((2*f) ^ rx)) = hwbf(feats[f]);
        } else {
            #pragma unroll
            for (int f = 20; f < 40; ++f)
                *(unsigned short*)(fb + ((2*f) ^ rx)) = hwbf(feats[f]);
            int same = (chain[n]==chain[jn]) & (batch[n]==batch[jn]);
            int rel = resi[jn] - resi[n];
            rel = (rel < -32 ? -32 : (rel > 32 ? 32 : rel)) + 32;
            meta[e] = same ? (rel + 1) : 0;
        }
    }
    WAIT_LGKM();

    const int rxl = (lrow & 7) << 4;

    // ---- feature GEMM (K=64): accF[e][p] ----
    f32x4 accF[2][8];
    #pragma unroll
    for (int ni = 0; ni < 2; ++ni)
        #pragma unroll
        for (int pb = 0; pb < 8; ++pb) accF[ni][pb] = (f32x4){0.f,0.f,0.f,0.f};
    #pragma unroll
    for (int ks = 0; ks < 2; ++ks) {
        bf16x8 a0 = *(const bf16x8*)(Fv + lrow*128       + ((16*lk + 64*ks) ^ rxl));
        bf16x8 a1 = *(const bf16x8*)(Fv + (16+lrow)*128  + ((16*lk + 64*ks) ^ rxl));
        #pragma unroll
        for (int pb = 0; pb < 8; ++pb) {
            bf16x8 b = *(const bf16x8*)(wftp_c + ((pb*2 + ks)*64 + lane)*16);
            accF[0][pb] = MFMA32(a0, b, accF[0][pb]);
            accF[1][pb] = MFMA32(a1, b, accF[1][pb]);
        }
    }

    // ---- W_rel add (fp32) + LayerNorm (DPP reduce, in-register) -> X bf16 natural layout ----
    {
        float lnSv[8], lnBv[8];
        #pragma unroll
        for (int pb = 0; pb < 8; ++pb) {
            lnSv[pb] = ln_scale[pb*16 + lrow];
            lnBv[pb] = ln_bias [pb*16 + lrow];
        }
        #pragma unroll
        for (int ni = 0; ni < 2; ++ni) {
            #pragma unroll
            for (int i = 0; i < 4; ++i) {
                int er = ni*16 + 4*lk + i;
                int mt = meta[er];
                const float* wrel = W_rel + (mt > 0 ? (mt-1)*128 : 0);
                float sv = (mt > 0) ? 1.f : 0.f;
                float s = 0.f, ss = 0.f;
                #pragma unroll
                for (int pb = 0; pb < 8; ++pb) {
                    float x = accF[ni][pb][i] + sv * wrel[pb*16 + lrow];
                    accF[ni][pb][i] = x;
                    s += x; ss += x*x;
                }
                s  = row16_sum(s);
                ss = row16_sum(ss);
                float mu  = s * 0.0078125f;
                float var = ss * 0.0078125f - mu*mu;
                float rstd = rsqrtf(var + 1e-5f);
                char* xb = Xv + er*256;
                const int rx2 = (er & 7) << 4;
                #pragma unroll
                for (int pb = 0; pb < 8; ++pb) {
                    float xv = (accF[ni][pb][i] - mu) * rstd * lnSv[pb] + lnBv[pb];
                    *(unsigned short*)(xb + ((2*(pb*16 + lrow)) ^ rx2)) = hwbf(xv);
                }
            }
        }
    }
    WAIT_LGKM();

    // ---- X frags held in registers for the whole MLP (natural k=p order) ----
    bf16x8 bx[2][4];
    #pragma unroll
    for (int ni = 0; ni < 2; ++ni)
        #pragma unroll
        for (int ks = 0; ks < 4; ++ks)
            bx[ni][ks] = *(const bf16x8*)(Xv + (ni*16+lrow)*256 + ((16*lk + 64*ks) ^ rxl));

    // ---- MLP: 8 slices of 32 h. GEMM1 (swapped, C1[h][e]) -> gelu in-reg -> GEMM2 (K=32) ----
    f32x4 acc2[2][8];
    #pragma unroll
    for (int ni = 0; ni < 2; ++ni)
        #pragma unroll
        for (int pt = 0; pt < 8; ++pt) acc2[ni][pt] = (f32x4){0.f,0.f,0.f,0.f};

    const float C2 = -2.30220797f;   // -2*sqrt(2/pi)*log2(e)
    #pragma unroll
    for (int hc = 0; hc < 8; ++hc) {
        f32x4 acc1[2][2];
        #pragma unroll
        for (int m = 0; m < 2; ++m)
            #pragma unroll
            for (int ni = 0; ni < 2; ++ni) acc1[m][ni] = (f32x4){0.f,0.f,0.f,0.f};
        #pragma unroll
        for (int ks = 0; ks < 4; ++ks) {
            bf16x8 a0 = *(const bf16x8*)(w1p_c + (((hc*2  )*4 + ks)*64 + lane)*16);
            bf16x8 a1 = *(const bf16x8*)(w1p_c + (((hc*2+1)*4 + ks)*64 + lane)*16);
            acc1[0][0] = MFMA32(a0, bx[0][ks], acc1[0][0]);
            acc1[0][1] = MFMA32(a0, bx[1][ks], acc1[0][1]);
            acc1[1][0] = MFMA32(a1, bx[0][ks], acc1[1][0]);
            acc1[1][1] = MFMA32(a1, bx[1][ks], acc1[1][1]);
        }
        f32x4 b1v[2];
        b1v[0] = *(const f32x4*)(b1 + hc*32      + 4*lk);
        b1v[1] = *(const f32x4*)(b1 + hc*32 + 16 + 4*lk);
        // gelu -> A-frag with k-slot j = m*4+i  (h_local = (j>>2)*16 + 4*lk + (j&3))
        short8v ga[2];
        #pragma unroll
        for (int m = 0; m < 2; ++m) {
            #pragma unroll
            for (int ni = 0; ni < 2; ++ni) {
                #pragma unroll
                for (int i = 0; i < 4; ++i) {
                    float x  = acc1[m][ni][i] + b1v[m][i];
                    float tt = x * __builtin_fmaf(0.044715f, x*x, 1.0f);
                    float ex = __builtin_amdgcn_exp2f(C2 * tt);
                    ga[ni][m*4+i] = (short)hwbf(x / (1.0f + ex));
                }
            }
        }
        bf16x8 ga0 = __builtin_bit_cast(bf16x8, ga[0]);
        bf16x8 ga1 = __builtin_bit_cast(bf16x8, ga[1]);
        #pragma unroll
        for (int pt = 0; pt < 8; ++pt) {
            bf16x8 wf = *(const bf16x8*)(w2p_c + ((pt*8 + hc)*64 + lane)*16);
            acc2[0][pt] = MFMA32(ga0, wf, acc2[0][pt]);
            acc2[1][pt] = MFMA32(ga1, wf, acc2[1][pt]);
        }
    }

    // ---- epilogue: + b2, fp32 store ----
    float b2v[8];
    #pragma unroll
    for (int pt = 0; pt < 8; ++pt) b2v[pt] = b2[pt*16 + lrow];
    #pragma unroll
    for (int ni = 0; ni < 2; ++ni) {
        #pragma unroll
        for (int pt = 0; pt < 8; ++pt) {
            #pragma unroll
            for (int i = 0; i < 4; ++i) {
                int er = ni*16 + 4*lk + i;
                out[(size_t)(edge0 + er)*128 + pt*16 + lrow] = acc2[ni][pt][i] + b2v[pt];
            }
        }
    }
}

extern "C" void kernel_launch(void* const* d_in, const int* in_sizes, int n_in,
                              void* d_out, int out_size, void* d_ws, size_t ws_size,
                              hipStream_t stream) {
    const float* pos      = (const float*)d_in[0];
    const int*   nbr      = (const int*)d_in[1];
    const int*   resi     = (const int*)d_in[2];
    const int*   chain    = (const int*)d_in[3];
    const int*   batch    = (const int*)d_in[4];
    const float* mask     = (const float*)d_in[5];
    const float* W_rel    = (const float*)d_in[6];
    const float* W_dist   = (const float*)d_in[7];
    const float* W_dir    = (const float*)d_in[8];
    const float* W_rot    = (const float*)d_in[9];
    const float* W_vec    = (const float*)d_in[10];
    const float* ln_scale = (const float*)d_in[11];
    const float* ln_bias  = (const float*)d_in[12];
    const float* W1       = (const float*)d_in[13];
    const float* b1       = (const float*)d_in[14];
    const float* W2       = (const float*)d_in[15];
    const float* b2       = (const float*)d_in[16];

    unsigned short* wftp = (unsigned short*)d_ws;         // 16 KB
    unsigned short* w1p  = wftp + 8192;                   // 64 KB
    unsigned short* w2p  = w1p + 32768;                   // 64 KB  (total 144 KB, proven)
    float* out  = (float*)d_out;
    float* outm = out + (size_t)NK * 128;

    sd_prep_weights<<<288, 256, 0, stream>>>(W1, W2, W_dist, W_dir, W_rot, W_vec,
                                             wftp, w1p, w2p);
    sd_mask_kernel<<<NK/256, 256, 0, stream>>>(nbr, mask, outm);
    sd_fused_kernel<<<NK/128, 256, 0, stream>>>(pos, nbr, resi, chain, batch, W_rel,
                                                ln_scale, ln_bias, b1, b2,
                                                (const char*)wftp, (const char*)w1p,
                                                (const char*)w2p, out);
}